// Round 14
// baseline (151.323 us; speedup 1.0000x reference)
//
#include <hip/hip_runtime.h>

#define B_ 32
#define N_ 8732
#define N2_ 17464
#define N4_ 4366      // N2_/4 exactly
#define C_ 21
#define NCLS 20
#define K_ 200
#define CONF_T 0.01f
#define NMS_T 0.45f
#define TPB_S 256
#define TPB_N 512
#define POOL 1024
#define RANKCAP 512   // refine-descent target (fallback refine path)
#define HB0 2048      // level-0 bins (shift 15)
#define HB 1024       // refine-level bins (shift 5 then 0)
#define BIN0 30791u   // 0x3C23D70B >> 15: bin offset for level 0

typedef unsigned long long u64;
typedef unsigned int u32;

// ---------------------------------------------------------------------------
// Kernel 1 (round-6 hardware-verified, unchanged): softmax over C=21.
// Coalesced float4->LDS staging, per-row compute in registers, DIRECT global
// dword stores per class plane. Grid: (ceil(N/256), B, 2 views).
// ---------------------------------------------------------------------------
__global__ __launch_bounds__(TPB_S) void softmax_kernel(
    const float* __restrict__ conf1, const float* __restrict__ conf2,
    float* __restrict__ scores)
{
  __shared__ float lds[TPB_S * C_];   // 21 KB
  const int t = threadIdx.x;
  const int tile = blockIdx.x * TPB_S;
  const int b = blockIdx.y;
  const int view = blockIdx.z;
  int cnt = N_ - tile; if (cnt > TPB_S) cnt = TPB_S;   // 256 or 28 (both %4==0)
  const float* conf = view ? conf2 : conf1;
  const float4* src = (const float4*)(conf + ((size_t)b * N_ + tile) * C_);  // 16B-aligned
  float4* l4 = (float4*)lds;
  const int n4 = (cnt * C_) >> 2;
  for (int i = t; i < n4; i += TPB_S) l4[i] = src[i];
  __syncthreads();
  if (t < cnt) {
    float x[C_];
#pragma unroll
    for (int i = 0; i < C_; ++i) x[i] = lds[t * C_ + i];  // stride-21: 2-way, free
    float m = x[0];
#pragma unroll
    for (int i = 1; i < C_; ++i) m = fmaxf(m, x[i]);
    float e[C_];
    float sum = 0.0f;
#pragma unroll
    for (int i = 0; i < C_; ++i) { e[i] = __expf(x[i] - m); sum += e[i]; }
    float inv = 1.0f / sum;   // one IEEE div, not 20
    float* o = scores + ((size_t)b * NCLS) * N2_ + (size_t)view * N_ + (tile + t);
#pragma unroll
    for (int c = 1; c < C_; ++c) { *o = e[c] * inv; o += N2_; }
  }
}

// ---------------------------------------------------------------------------
// Kernel 2 (round-11 hardware-verified, 55.6 µs — best measured): per-
// (image,class). Phases: register score load -> shift-15 2048-bin histogram
// (fused suffix-scan + bin-select, one barrier saved) -> [rare refine] ->
// count/scan/write collect (pool order irrelevant: keys unique) -> b128
// all-pairs rank-by-counting -> decode -> triangle IoU (row-halves,
// scattered pipelined reads + atomicOr; word-aligned variant REGRESSED:
// same-address b128 is not a free broadcast, conflicts 846K->987K) ->
// word-chunked static greedy scan -> in-wave compact. Out-slice zeroing
// fused. One 512-thread block per (b, c); grid 640 (all co-resident).
// ---------------------------------------------------------------------------
__global__ __launch_bounds__(TPB_N, 2) void nms_kernel(
    const float* __restrict__ scores,
    const float4* __restrict__ loc1,
    const float4* __restrict__ loc2,
    const float4* __restrict__ dbox,
    float* __restrict__ out)
{
  const int t = threadIdx.x;
  const int lane = t & 63;
  const int wv = t >> 6;
  const int bimg = blockIdx.x / NCLS;
  const int cls = 1 + (blockIdx.x % NCLS);
  const float4* sc4 = (const float4*)(scores + ((size_t)bimg * NCLS + (cls - 1)) * N2_);
  float* ob = out + ((size_t)bimg * C_ + cls) * K_ * 5;

  __shared__ u32 hist[HB0];              // 8 KB (L0: 2048 @shift15; refine: first 1024)
  __shared__ u64 pool[POOL] __attribute__((aligned(16)));  // 8 KB, pre-zeroed
  __shared__ u64 spool[256];             // 2 KB, rank-ordered top-200
  __shared__ float4 bb[K_];              // 3.2 KB
  __shared__ float bar[K_];
  __shared__ u64 rowmask[K_][4];         // 6.4 KB (triangle: row j has cols>j)
  __shared__ u64 validmask[4];
  __shared__ u32 wtot[8];
  __shared__ u32 sh_sel, sh_Sb, sh_Sn, sh_nc, sh_total;

  // ---- fused output zeroing (replaces hipMemsetAsync) ----
  {
    const float4 z4 = make_float4(0.f, 0.f, 0.f, 0.f);
    if (t < 250) ((float4*)ob)[t] = z4;                      // own (b,cls) slice
    if (cls == 1 && t >= 256 && t < 506)                     // background class 0
      ((float4*)(out + (size_t)bimg * C_ * K_ * 5))[t - 256] = z4;
  }

  // ---- load this (b,c)'s 17464 scores into registers: the ONLY global pass ----
  float4 v[9];
#pragma unroll
  for (int k = 0; k < 9; ++k) {
    int i = t + k * TPB_N;
    v[k] = (i < N4_) ? sc4[i] : make_float4(0.f, 0.f, 0.f, 0.f);
  }

  // ---- zero L0 hist (2048) + pool + spool ----
  hist[t] = 0u; hist[t + 512] = 0u; hist[t + 1024] = 0u; hist[t + 1536] = 0u;
  pool[t] = 0ULL; pool[t + TPB_N] = 0ULL;
  if (t < 256) spool[t] = 0ULL;
  __syncthreads();

  // ---- level 0: 2048-bin histogram at shift 15 ----
  // valid keys 0x3C23D70B..0x3F800000 -> (key>>15)-30791 in [0,1721]
#pragma unroll
  for (int k = 0; k < 9; ++k) {
    float ss[4] = {v[k].x, v[k].y, v[k].z, v[k].w};
#pragma unroll
    for (int c2 = 0; c2 < 4; ++c2) {
      float s = ss[c2];
      if (s > CONF_T)
        atomicAdd(&hist[(__float_as_uint(s) >> 15) - BIN0], 1u);
    }
  }
  __syncthreads();

  // ---- suffix sums over 2048 bins + FUSED bin select ----
  // Thread t owns bins 4t..4t+3 with suffix sums S0..S3; S4 = after_me is
  // the suffix of bin 4t+4. Every adjacent pair (h,h+1) checked inline.
  {
    u32 c0 = hist[4 * t + 0], c1 = hist[4 * t + 1];
    u32 c2b = hist[4 * t + 2], c3 = hist[4 * t + 3];
    u32 T = c0 + c1 + c2b + c3;
    u32 x = T;
#pragma unroll
    for (int off = 1; off < 64; off <<= 1) {
      u32 y = __shfl_down(x, off);
      if (lane + off < 64) x += y;
    }                                   // x = suffix-incl sum of thread totals in wave
    if (lane == 0) wtot[wv] = x;
    __syncthreads();
    u32 wafter = 0;
    for (int w = wv + 1; w < 8; ++w) wafter += wtot[w];
    u32 after_me = (x - T) + wafter;    // totals of threads strictly after t
    u32 S4 = after_me;
    u32 S3 = c3 + S4, S2 = c2b + S3, S1 = c1 + S2, S0 = c0 + S1;
    if (t == 0) sh_total = S0;          // total valid count
    if (S0 >= (u32)K_ && S1 < (u32)K_) { sh_sel = 4u * t + 0u; sh_Sb = S0; sh_Sn = S1; }
    if (S1 >= (u32)K_ && S2 < (u32)K_) { sh_sel = 4u * t + 1u; sh_Sb = S1; sh_Sn = S2; }
    if (S2 >= (u32)K_ && S3 < (u32)K_) { sh_sel = 4u * t + 2u; sh_Sb = S2; sh_Sn = S3; }
    if (S3 >= (u32)K_ && S4 < (u32)K_) { sh_sel = 4u * t + 3u; sh_Sb = S3; sh_Sn = S4; }
  }
  __syncthreads();

  u32 loKey, prefix = 0, Gacc = 0;
  bool needMore = false;
  {
    u32 total = sh_total;               // block-uniform
    if (total < (u32)K_) {
      loKey = 1u;                       // undershoot: take all valid (<200)
    } else {
      prefix = sh_sel + BIN0;           // real key>>15 value
      loKey = prefix << 15;
      Gacc = sh_Sn;
      needMore = sh_Sb > (u32)RANKCAP;  // rare: one 32768-key window holding >312
    }
  }

  // ---- refine levels (rare): shift 5 (1024 bins) then shift 0 (32 bins) ----
  for (int lvl = 1; lvl <= 2 && needMore; ++lvl) {
    const int shift = (lvl == 1) ? 5 : 0;
    const int mshift = (lvl == 1) ? 15 : 5;
    const u32 bmask = (lvl == 1) ? 1023u : 31u;
    for (int h = t; h < HB; h += TPB_N) hist[h] = 0u;
    __syncthreads();
#pragma unroll
    for (int k = 0; k < 9; ++k) {
      float ss[4] = {v[k].x, v[k].y, v[k].z, v[k].w};
#pragma unroll
      for (int c2 = 0; c2 < 4; ++c2) {
        float s = ss[c2];
        if (s > CONF_T) {
          u32 key = __float_as_uint(s);
          if ((key >> mshift) == prefix)
            atomicAdd(&hist[(key >> shift) & bmask], 1u);
        }
      }
    }
    __syncthreads();
    // suffix sums over 1024 bins: 2 bins/thread + wave scan
    u32 c0 = hist[2 * t], c1 = hist[2 * t + 1];
    u32 T = c0 + c1;
    u32 x = T;
#pragma unroll
    for (int off = 1; off < 64; off <<= 1) {
      u32 y = __shfl_down(x, off);
      if (lane + off < 64) x += y;
    }
    if (lane == 0) wtot[wv] = x;
    __syncthreads();
    u32 wafter = 0;
    for (int w = wv + 1; w < 8; ++w) wafter += wtot[w];
    u32 after_me = (x - T) + wafter;
    u32 S2 = after_me;
    u32 S1 = c1 + S2, S0 = c0 + S1;
    u32 need = (u32)K_ - Gacc;
    if (S0 >= need && S1 < need) { sh_sel = 2u * t + 0u; sh_Sb = S0; sh_Sn = S1; }
    if (S1 >= need && S2 < need) { sh_sel = 2u * t + 1u; sh_Sb = S1; sh_Sn = S2; }
    __syncthreads();
    prefix = (prefix << ((lvl == 1) ? 10 : 5)) | sh_sel;
    u32 candTotal = Gacc + sh_Sb;
    Gacc += sh_Sn;
    loKey = prefix << shift;
    needMore = (candTotal > (u32)RANKCAP) && (lvl < 2);
  }

  // ---- collect: count -> block scan -> per-thread sequential writes ----
  // (pool order is irrelevant: keys unique -> rank-by-counting invariant)
  {
    u32 mycnt = 0;
#pragma unroll
    for (int k = 0; k < 9; ++k) {
      float ss[4] = {v[k].x, v[k].y, v[k].z, v[k].w};
#pragma unroll
      for (int c2 = 0; c2 < 4; ++c2)
        mycnt += (ss[c2] > CONF_T && __float_as_uint(ss[c2]) >= loKey) ? 1u : 0u;
    }
    u32 inc = mycnt;
#pragma unroll
    for (int off = 1; off < 64; off <<= 1) {
      u32 y = __shfl_up(inc, off);
      if (lane >= off) inc += y;
    }                                   // wave-inclusive scan
    if (lane == 63) wtot[wv] = inc;
    __syncthreads();
    u32 wbase = 0;
    for (int w = 0; w < wv; ++w) wbase += wtot[w];
    u32 pos = wbase + (inc - mycnt);    // block-exclusive offset
    if (t == TPB_N - 1) sh_nc = wbase + inc;
#pragma unroll
    for (int k = 0; k < 9; ++k) {
      int i = t + k * TPB_N;
      float ss[4] = {v[k].x, v[k].y, v[k].z, v[k].w};
#pragma unroll
      for (int c2 = 0; c2 < 4; ++c2) {
        float s = ss[c2];
        u32 key = __float_as_uint(s);
        if (s > CONF_T && key >= loKey) {
          if (pos < (u32)POOL)
            pool[pos] = ((u64)key << 32) | (u64)(0xFFFFFFFFu - (u32)(i * 4 + c2));
          ++pos;
        }
      }
    }
  }
  __syncthreads();

  // ---- rank-by-counting: composite keys unique -> rank = #{keys > mine} ----
  // pool pre-zeroed, so b128 reads past nc compare against 0 (harmless).
  u32 nc = sh_nc < (u32)POOL ? sh_nc : (u32)POOL;
  const bool dual = nc > (u32)TPB_N;    // block-uniform; rare (lvl-2 exit >512)
  u64 my0 = (t < (int)nc) ? pool[t] : 0ULL;
  u64 my1 = (dual && t + TPB_N < (int)nc) ? pool[t + TPB_N] : 0ULL;
  u32 r0 = 0, r1 = 0;
  if ((u32)(t & ~63) < nc) {            // whole waves past nc skip the loop
    if (!dual) {
#pragma unroll 4
      for (u32 k = 0; k < nc; k += 2) { // 2 keys per ds_read_b128
        ulonglong2 pk = *(const ulonglong2*)&pool[k];
        r0 += (pk.x > my0) ? 1u : 0u;
        r0 += (pk.y > my0) ? 1u : 0u;
      }
    } else {
#pragma unroll 4
      for (u32 k = 0; k < nc; k += 2) {
        ulonglong2 pk = *(const ulonglong2*)&pool[k];
        r0 += (pk.x > my0) ? 1u : 0u;
        r0 += (pk.y > my0) ? 1u : 0u;
        r1 += (pk.x > my1) ? 1u : 0u;
        r1 += (pk.y > my1) ? 1u : 0u;
      }
    }
  }
  if (my0 != 0ULL && r0 < (u32)K_) spool[r0] = my0;
  if (dual && my1 != 0ULL && r1 < (u32)K_) spool[r1] = my1;
  __syncthreads();
  // spool[0..199] == exact top_k (desc score, ties by ascending index)

  // ---- decode boxes for top-200; idle threads 256+ zero rowmask ----
  float scv = 0.f;
  if (t < K_) {
    float x1 = 0.f, y1 = 0.f, x2 = 0.f, y2 = 0.f, area = 0.f;
    u64 e = spool[t];
    u32 kb = (u32)(e >> 32);
    if (kb != 0u) {
      scv = __uint_as_float(kb);
      u32 idx = 0xFFFFFFFFu - (u32)(e & 0xFFFFFFFFu);
      int nn = (idx < (u32)N_) ? (int)idx : (int)(idx - N_);
      float4 l = (idx < (u32)N_) ? loc1[(size_t)bimg * N_ + nn]
                                 : loc2[(size_t)bimg * N_ + nn];
      float4 d = dbox[nn];
      float cx = d.x + l.x * 0.1f * d.z;
      float cy = d.y + l.y * 0.1f * d.w;
      float w = d.z * __expf(l.z * 0.2f);
      float h = d.w * __expf(l.w * 0.2f);
      x1 = cx - w * 0.5f; y1 = cy - h * 0.5f;
      x2 = cx + w * 0.5f; y2 = cy + h * 0.5f;
      if (idx >= (u32)N_) {   // horizontal flip of second (TTA) view
        float tmp = 1.0f - x2; x2 = 1.0f - x1; x1 = tmp;
      }
      area = (x2 - x1) * (y2 - y1);
    }
    bb[t] = make_float4(x1, y1, x2, y2);
    bar[t] = area;
  } else if (t >= 256) {
    for (int i = t - 256; i < 4 * K_; i += 256) ((u64*)rowmask)[i] = 0ULL;
  }
  {
    bool myvalid = (t < K_) && (scv > CONF_T);
    u64 bal = __ballot(myvalid);
    if (lane == 0 && wv < 4) validmask[wv] = bal;
  }
  __syncthreads();

  // ---- triangle IoU: row j, cols j+1..199, split in half across 400 threads ----
  if (t < 2 * K_) {
    const int j = (t < K_) ? t : (t - K_);
    const int h = (t < K_) ? 0 : 1;
    const int L = K_ - 1 - j;             // #cols after j
    const int half = (L + 1) >> 1;
    const int s0c = j + 1 + (h ? half : 0);
    const int e0c = h ? K_ : (j + 1 + half);
    if (s0c < e0c) {
      float4 mb = bb[j];
      float ma = bar[j];
      for (int w = (s0c >> 6); w <= ((e0c - 1) >> 6); ++w) {
        int ka = (w << 6) > s0c ? (w << 6) : s0c;
        int kb2 = ((w + 1) << 6) < e0c ? ((w + 1) << 6) : e0c;
        u64 m = 0ULL;
        for (int k2 = ka; k2 < kb2; ++k2) {
          float4 obx = bb[k2];
          float ox1 = fmaxf(mb.x, obx.x);
          float oy1 = fmaxf(mb.y, obx.y);
          float ox2 = fminf(mb.z, obx.z);
          float oy2 = fminf(mb.w, obx.w);
          float inter = fmaxf(ox2 - ox1, 0.f) * fmaxf(oy2 - oy1, 0.f);
          float uni = ma + bar[k2] - inter;
          m |= (inter > NMS_T * uni) ? (1ULL << (k2 & 63)) : 0ULL;
        }
        if (m) atomicOr(&rowmask[j][w], m);
      }
    }
  }
  __syncthreads();
  // waves 1-7 are done; wave 0 finishes the block alone.

  // ---- static pipelined greedy scan, chunked by word (triangle: j>=64 never
  // touches word 0, etc.), then in-wave compact ----
  if (t < 64) {
    const u64 vv0 = validmask[0], vv1 = validmask[1];
    const u64 vv2 = validmask[2], vv3 = validmask[3];
    u64 s0 = 0, s1 = 0, s2 = 0, s3 = 0;
    u64 k0 = 0, k1 = 0, k2m = 0, k3 = 0;
#pragma unroll 8
    for (int j = 0; j < 64; ++j) {
      u64 q0 = rowmask[j][0], q1 = rowmask[j][1], q2 = rowmask[j][2], q3 = rowmask[j][3];
      u64 bit = 1ULL << j;
      if ((vv0 & bit) && !(s0 & bit)) { s0 |= q0; s1 |= q1; s2 |= q2; s3 |= q3; k0 |= bit; }
    }
#pragma unroll 8
    for (int j = 64; j < 128; ++j) {
      u64 q1 = rowmask[j][1], q2 = rowmask[j][2], q3 = rowmask[j][3];
      u64 bit = 1ULL << (j & 63);
      if ((vv1 & bit) && !(s1 & bit)) { s1 |= q1; s2 |= q2; s3 |= q3; k1 |= bit; }
    }
#pragma unroll 8
    for (int j = 128; j < 192; ++j) {
      u64 q2 = rowmask[j][2], q3 = rowmask[j][3];
      u64 bit = 1ULL << (j & 63);
      if ((vv2 & bit) && !(s2 & bit)) { s2 |= q2; s3 |= q3; k2m |= bit; }
    }
#pragma unroll
    for (int j = 192; j < K_; ++j) {
      u64 q3 = rowmask[j][3];
      u64 bit = 1ULL << (j & 63);
      if ((vv3 & bit) && !(s3 & bit)) { s3 |= q3; k3 |= bit; }
    }
    // ---- compact kept entries (lane-parallel within wave 0) ----
    const u32 n0 = (u32)__popcll(k0);
    const u32 n01 = n0 + (u32)__popcll(k1);
    const u32 n012 = n01 + (u32)__popcll(k2m);
    const u64 below = (1ULL << lane) - 1ULL;
#pragma unroll
    for (int w = 0; w < 4; ++w) {
      int j = (w << 6) + lane;
      if (j < K_) {
        u64 kw = (w == 0) ? k0 : (w == 1) ? k1 : (w == 2) ? k2m : k3;
        if ((kw >> lane) & 1ULL) {
          int pos2 = (int)__popcll(kw & below)
                  + (int)((w == 0) ? 0u : (w == 1) ? n0 : (w == 2) ? n01 : n012);
          u64 e = spool[j];
          float sc = __uint_as_float((u32)(e >> 32));
          float4 bx = bb[j];
          float* o = ob + (size_t)pos2 * 5;
          o[0] = sc; o[1] = bx.x; o[2] = bx.y; o[3] = bx.z; o[4] = bx.w;
        }
      }
    }
  }
}

extern "C" void kernel_launch(void* const* d_in, const int* in_sizes, int n_in,
                              void* d_out, int out_size, void* d_ws, size_t ws_size,
                              hipStream_t stream) {
  const float* loc1 = (const float*)d_in[0];
  const float* conf1 = (const float*)d_in[1];
  const float* loc2 = (const float*)d_in[2];
  const float* conf2 = (const float*)d_in[3];
  const float* dbox = (const float*)d_in[4];
  float* out = (float*)d_out;
  float* scores = (float*)d_ws;   // [B, NCLS, 2N] fp32 = 44.7 MB

  dim3 g1((N_ + TPB_S - 1) / TPB_S, B_, 2);
  softmax_kernel<<<g1, TPB_S, 0, stream>>>(conf1, conf2, scores);

  nms_kernel<<<B_ * NCLS, TPB_N, 0, stream>>>(
      scores, (const float4*)loc1, (const float4*)loc2, (const float4*)dbox, out);
}